// Round 3
// baseline (862.207 us; speedup 1.0000x reference)
//
#include <hip/hip_runtime.h>
#include <hip/hip_bf16.h>

typedef __bf16 bf16x8 __attribute__((ext_vector_type(8)));
typedef float  f32x4  __attribute__((ext_vector_type(4)));
typedef short  s16x4  __attribute__((ext_vector_type(4)));

#define D_MODEL 1024
#define SEQ 2048
#define BS 4
#define NH 16
#define DH 64
#define MTOT (BS * SEQ) /* 8192 */

#define AS1 __attribute__((address_space(1)))
#define AS3 __attribute__((address_space(3)))

template <typename T>
__device__ inline bf16x8 ld8(const T* p);

template <>
__device__ inline bf16x8 ld8<float>(const float* p) {
    f32x4 a = *(const f32x4*)p;
    f32x4 b = *(const f32x4*)(p + 4);
    bf16x8 r;
    r[0] = (__bf16)a[0]; r[1] = (__bf16)a[1]; r[2] = (__bf16)a[2]; r[3] = (__bf16)a[3];
    r[4] = (__bf16)b[0]; r[5] = (__bf16)b[1]; r[6] = (__bf16)b[2]; r[7] = (__bf16)b[3];
    return r;
}

template <>
__device__ inline bf16x8 ld8<__bf16>(const __bf16* p) {
    return *(const bf16x8*)p;
}

// ---------------------------------------------------------------------------
// fp32 -> bf16 weight conversion (4 matrices of NW elems each).
// ---------------------------------------------------------------------------
__global__ __launch_bounds__(256) void cvt4_kernel(
    const float* __restrict__ a, const float* __restrict__ b,
    const float* __restrict__ c, const float* __restrict__ e,
    __bf16* __restrict__ x, __bf16* __restrict__ y,
    __bf16* __restrict__ z, __bf16* __restrict__ w)
{
    const float* s = (blockIdx.y == 0) ? a : (blockIdx.y == 1) ? b : (blockIdx.y == 2) ? c : e;
    __bf16*      d = (blockIdx.y == 0) ? x : (blockIdx.y == 1) ? y : (blockIdx.y == 2) ? z : w;
    const long i = ((long)blockIdx.x * 256 + threadIdx.x) * 8;
    *(bf16x8*)(d + i) = ld8<float>(s + i);
}

// ---------------------------------------------------------------------------
// QKV projections, one dispatch (z selects A,B,C). BK=64 as two BK=32 panels.
// A fp32 -> bf16 through VGPRs; B bf16 via global_load_lds width=16.
// ---------------------------------------------------------------------------
__global__ __launch_bounds__(256) void gemm_qkv(
    const float* __restrict__ q, const float* __restrict__ k, const float* __restrict__ v,
    const __bf16* __restrict__ Wb,
    __bf16* __restrict__ Qp, __bf16* __restrict__ Kp, __bf16* __restrict__ Vp)
{
    __shared__ __align__(16) __bf16 As[2 * 4096];
    __shared__ __align__(16) __bf16 Bs[2 * 4096];
    const int K = D_MODEL, N = D_MODEL;
    const int z = blockIdx.z;
    const float* A = (z == 0) ? q : (z == 1) ? k : v;
    const __bf16* B = Wb + (long)z * D_MODEL * D_MODEL;
    __bf16* C = (z == 0) ? Qp : (z == 1) ? Kp : Vp;

    const int t = threadIdx.x;
    const int wave = t >> 6, lane = t & 63;
    const int quad = lane >> 4, l15 = lane & 15;
    const int wm = (wave >> 1) * 64, wn = (wave & 1) * 64;
    const long m0 = (long)blockIdx.x * 128;
    const long n0 = (long)blockIdx.y * 128;
    const int sr = t >> 2, sc = (t & 3) * 8;

    const __bf16* gB = B + (n0 + sr) * (long)K + sc;
    __bf16* lB0 = Bs + wave * 512;
    __bf16* lB1 = Bs + 2048 + wave * 512;
    __bf16* lB2 = Bs + 4096 + wave * 512;
    __bf16* lB3 = Bs + 6144 + wave * 512;

    f32x4 acc[4][4] = {};

    for (int k0 = 0; k0 < K; k0 += 64) {
        __builtin_amdgcn_global_load_lds((const AS1 void*)(gB + k0),               (AS3 void*)lB0, 16, 0, 0);
        __builtin_amdgcn_global_load_lds((const AS1 void*)(gB + 64 * K + k0),      (AS3 void*)lB1, 16, 0, 0);
        __builtin_amdgcn_global_load_lds((const AS1 void*)(gB + k0 + 32),          (AS3 void*)lB2, 16, 0, 0);
        __builtin_amdgcn_global_load_lds((const AS1 void*)(gB + 64 * K + k0 + 32), (AS3 void*)lB3, 16, 0, 0);
        *(bf16x8*)&As[sr * 32 + sc]               = ld8<float>(&A[(m0 + sr) * K + k0 + sc]);
        *(bf16x8*)&As[(sr + 64) * 32 + sc]        = ld8<float>(&A[(m0 + sr + 64) * K + k0 + sc]);
        *(bf16x8*)&As[4096 + sr * 32 + sc]        = ld8<float>(&A[(m0 + sr) * K + k0 + 32 + sc]);
        *(bf16x8*)&As[4096 + (sr + 64) * 32 + sc] = ld8<float>(&A[(m0 + sr + 64) * K + k0 + 32 + sc]);
        __syncthreads();
#pragma unroll
        for (int p = 0; p < 2; ++p) {
            bf16x8 af[4], bfr[4];
#pragma unroll
            for (int i = 0; i < 4; ++i) af[i]  = *(const bf16x8*)&As[p * 4096 + (wm + i * 16 + l15) * 32 + quad * 8];
#pragma unroll
            for (int i = 0; i < 4; ++i) bfr[i] = *(const bf16x8*)&Bs[p * 4096 + (wn + i * 16 + l15) * 32 + quad * 8];
#pragma unroll
            for (int i = 0; i < 4; ++i)
#pragma unroll
                for (int j = 0; j < 4; ++j)
                    acc[i][j] = __builtin_amdgcn_mfma_f32_16x16x32_bf16(af[i], bfr[j], acc[i][j], 0, 0, 0);
        }
        __syncthreads();
    }

#pragma unroll
    for (int i = 0; i < 4; ++i)
#pragma unroll
        for (int j = 0; j < 4; ++j) {
            const long r = m0 + wm + i * 16 + quad * 4;
            const long c = n0 + wn + j * 16 + l15;
#pragma unroll
            for (int reg = 0; reg < 4; ++reg)
                C[(r + reg) * N + c] = (__bf16)acc[i][j][reg];
        }
}

// ---------------------------------------------------------------------------
// bf16 GEMM for ctx @ Wo^T: two-panel BK=64, both operands via global_load_lds.
// ---------------------------------------------------------------------------
__global__ __launch_bounds__(256) void gemm_bb(
    const __bf16* __restrict__ A, const __bf16* __restrict__ B,
    __bf16* __restrict__ C, int M, int N, int K)
{
    __shared__ __align__(16) __bf16 As[2 * 4096];
    __shared__ __align__(16) __bf16 Bs[2 * 4096];
    const int t = threadIdx.x;
    const int wave = t >> 6, lane = t & 63;
    const int quad = lane >> 4, l15 = lane & 15;
    const int wm = (wave >> 1) * 64, wn = (wave & 1) * 64;
    const long m0 = (long)blockIdx.x * 128;
    const long n0 = (long)blockIdx.y * 128;
    const int sr = t >> 2, sc = (t & 3) * 8;

    const __bf16* gA = A + (m0 + sr) * (long)K + sc;
    const __bf16* gB = B + (n0 + sr) * (long)K + sc;
    __bf16* lA0 = As + wave * 512;
    __bf16* lA1 = As + 2048 + wave * 512;
    __bf16* lA2 = As + 4096 + wave * 512;
    __bf16* lA3 = As + 6144 + wave * 512;
    __bf16* lB0 = Bs + wave * 512;
    __bf16* lB1 = Bs + 2048 + wave * 512;
    __bf16* lB2 = Bs + 4096 + wave * 512;
    __bf16* lB3 = Bs + 6144 + wave * 512;

    f32x4 acc[4][4] = {};

    for (int k0 = 0; k0 < K; k0 += 64) {
        __builtin_amdgcn_global_load_lds((const AS1 void*)(gA + k0),               (AS3 void*)lA0, 16, 0, 0);
        __builtin_amdgcn_global_load_lds((const AS1 void*)(gA + 64 * K + k0),      (AS3 void*)lA1, 16, 0, 0);
        __builtin_amdgcn_global_load_lds((const AS1 void*)(gA + k0 + 32),          (AS3 void*)lA2, 16, 0, 0);
        __builtin_amdgcn_global_load_lds((const AS1 void*)(gA + 64 * K + k0 + 32), (AS3 void*)lA3, 16, 0, 0);
        __builtin_amdgcn_global_load_lds((const AS1 void*)(gB + k0),               (AS3 void*)lB0, 16, 0, 0);
        __builtin_amdgcn_global_load_lds((const AS1 void*)(gB + 64 * K + k0),      (AS3 void*)lB1, 16, 0, 0);
        __builtin_amdgcn_global_load_lds((const AS1 void*)(gB + k0 + 32),          (AS3 void*)lB2, 16, 0, 0);
        __builtin_amdgcn_global_load_lds((const AS1 void*)(gB + 64 * K + k0 + 32), (AS3 void*)lB3, 16, 0, 0);
        __syncthreads();
#pragma unroll
        for (int p = 0; p < 2; ++p) {
            bf16x8 af[4], bfr[4];
#pragma unroll
            for (int i = 0; i < 4; ++i) af[i]  = *(const bf16x8*)&As[p * 4096 + (wm + i * 16 + l15) * 32 + quad * 8];
#pragma unroll
            for (int i = 0; i < 4; ++i) bfr[i] = *(const bf16x8*)&Bs[p * 4096 + (wn + i * 16 + l15) * 32 + quad * 8];
#pragma unroll
            for (int i = 0; i < 4; ++i)
#pragma unroll
                for (int j = 0; j < 4; ++j)
                    acc[i][j] = __builtin_amdgcn_mfma_f32_16x16x32_bf16(af[i], bfr[j], acc[i][j], 0, 0, 0);
        }
        __syncthreads();
    }

#pragma unroll
    for (int i = 0; i < 4; ++i)
#pragma unroll
        for (int j = 0; j < 4; ++j) {
            const long r = m0 + wm + i * 16 + quad * 4;
            const long c = n0 + wn + j * 16 + l15;
#pragma unroll
            for (int reg = 0; reg < 4; ++reg)
                C[(r + reg) * N + c] = (__bf16)acc[i][j][reg];
        }
}

// exp2 quad + packed bf16 cvt: st (4 scores) + mask bias -> 16x16x16 A-frag.
__device__ inline s16x4 exp_quad(const f32x4 st, const f32x4 mv, float C1) {
    float p0 = __builtin_amdgcn_exp2f(fmaf(st[0], C1, mv[0]));
    float p1 = __builtin_amdgcn_exp2f(fmaf(st[1], C1, mv[1]));
    float p2 = __builtin_amdgcn_exp2f(fmaf(st[2], C1, mv[2]));
    float p3 = __builtin_amdgcn_exp2f(fmaf(st[3], C1, mv[3]));
    union { __hip_bfloat162 h2[2]; s16x4 s; } u;
    u.h2[0] = __float22bfloat162_rn(float2{p0, p1});
    u.h2[1] = __float22bfloat162_rn(float2{p2, p3});
    return u.s;
}

// ---------------------------------------------------------------------------
// Flash attention v8 = v7 pipeline with the per-wave serial chain broken:
//  - both q-tiles' S computed first (st0, st1), then QK(1) MFMAs interleaved
//    with exp(0) VALU quads, PV(0) MFMAs interleaved with exp(1) quads —
//    every MFMA cluster has independent VALU work in its shadow (dual-pipe
//    issue within one wave; m114 overlap + T15 dual-state idea).
//  - s_setprio(1) across the compute phase (T5: +4-7% on multi-wave attn).
//  - grid swapped to (bh, qt): the 16 qt-blocks sharing one (b,h)'s K/V are
//    64-apart in dispatch order -> same XCD L2 (round-robin %8) -> K/V
//    fetched once per XCD instead of 8x (FETCH 139MB -> ~65MB predicted).
//  - __launch_bounds__(256,4) pins VGPR<=128 (4 waves/SIMD preserved).
// ---------------------------------------------------------------------------
__global__ __launch_bounds__(256, 4) void attn_kernel(
    const __bf16* Qp, const __bf16* __restrict__ Kp, const __bf16* __restrict__ Vp,
    const float* __restrict__ mask, __bf16* Ctx)
{
    __shared__ __align__(16) __bf16 Ks[2][64][72];   // [buf][key][d]
    __shared__ __align__(16) __bf16 Vt[2][64][76];   // [buf][d][key], rows 152B
    __shared__ __align__(16) float  Ms[2][64];       // mask * -1e9 * log2e

    const int t = threadIdx.x;
    const int wave = t >> 6, lane = t & 63;
    const int quad = lane >> 4, l15 = lane & 15;
    const int bh = blockIdx.x;            // 0..63  (fast dim -> XCD affinity)
    const int qt = blockIdx.y;            // 0..15
    const int b = bh >> 4, h = bh & 15;
    const long rowbase = (long)b * SEQ;
    const int q0 = qt * 128 + wave * 16;

    // Q fragments, B-operand layout (q=l15, d=quad*8+j), 2 q-tiles.
    bf16x8 aq[2][2];
#pragma unroll
    for (int qi = 0; qi < 2; ++qi) {
        const long qrow = rowbase + q0 + qi * 64 + l15;
        const __bf16* qptr = Qp + qrow * D_MODEL + h * DH + quad * 8;
        aq[qi][0] = *(const bf16x8*)(qptr);
        aq[qi][1] = *(const bf16x8*)(qptr + 32);
    }

    // ones B-fragment for the l-MFMA (bf16 1.0 = 0x3F80)
    const s16x4 ones = {(short)0x3F80, (short)0x3F80, (short)0x3F80, (short)0x3F80};

    f32x4 acc_l[2] = {};      // [qi]; C-layout rows q=quad*4+reg (cols identical)
    f32x4 acc_o[2][4] = {};   // [qi][d-tile]; C-layout: d=dt*16+l15, q=quad*4+reg

    const int sr = t >> 2, sc = (t & 3) * 16;        // K staging
    const int kp2 = (t >> 3) * 2, dc = (t & 7) * 8;  // V staging (key pairs)
    const float C1 = 0.125f * 1.44269504f;
    const float C2 = -1e9f * 1.44269504f;

    // register staging bases
    const __bf16* kbase = Kp + (rowbase + sr) * D_MODEL + h * DH + sc;
    const __bf16* vbase = Vp + (rowbase + kp2) * D_MODEL + h * DH + dc;

    // prologue: stage tile 0 into registers
    bf16x8 kr0 = *(const bf16x8*)(kbase);
    bf16x8 kr1 = *(const bf16x8*)(kbase + 8);
    bf16x8 vr0 = *(const bf16x8*)(vbase);
    bf16x8 vr1 = *(const bf16x8*)(vbase + D_MODEL);
    float  mreg = (t < 64) ? mask[rowbase + t] * C2 : 0.f;

    for (int kt = 0; kt < SEQ / 64; ++kt) {
        const int buf = kt & 1;
        // ---- write staged registers -> LDS[buf] ----
        *(bf16x8*)&Ks[buf][sr][sc]     = kr0;
        *(bf16x8*)&Ks[buf][sr][sc + 8] = kr1;
#pragma unroll
        for (int e = 0; e < 8; ++e) {
            union { __bf16 h2[2]; unsigned u; } pk;
            pk.h2[0] = vr0[e]; pk.h2[1] = vr1[e];
            *(unsigned*)&Vt[buf][dc + e][kp2] = pk.u;
        }
        if (t < 64) Ms[buf][t] = mreg;
        __syncthreads();

        // ---- issue tile kt+1 global loads; consumed before the next barrier ----
        {
            const int ktn = (kt + 1 < SEQ / 64) ? kt + 1 : kt;
            const long off = (long)ktn * 64 * D_MODEL;
            kr0 = *(const bf16x8*)(kbase + off);
            kr1 = *(const bf16x8*)(kbase + off + 8);
            vr0 = *(const bf16x8*)(vbase + off);
            vr1 = *(const bf16x8*)(vbase + off + D_MODEL);
            mreg = (t < 64) ? mask[rowbase + ktn * 64 + t] * C2 : 0.f;
        }

        // ---- hoisted fragments (shared by both q-tiles) ----
        bf16x8 kf[4][2];     // A-op: K[key=nt*16+l15][d=ks*32+quad*8+j]
#pragma unroll
        for (int nt = 0; nt < 4; ++nt)
#pragma unroll
            for (int ks = 0; ks < 2; ++ks)
                kf[nt][ks] = *(const bf16x8*)&Ks[buf][nt * 16 + l15][ks * 32 + quad * 8];
        s16x4 vtf[4][4];     // B-op (16x16x16): V[key=nt*16+quad*4+e][d=dt*16+l15]
#pragma unroll
        for (int nt = 0; nt < 4; ++nt)
#pragma unroll
            for (int dt = 0; dt < 4; ++dt)
                vtf[nt][dt] = *(const s16x4*)&Vt[buf][dt * 16 + l15][nt * 16 + quad * 4];
        f32x4 mv[4];         // mask bias, elem reg -> key nt*16+quad*4+reg
#pragma unroll
        for (int nt = 0; nt < 4; ++nt)
            mv[nt] = *(const f32x4*)&Ms[buf][nt * 16 + quad * 4];

        // ---- compute: MFMA clusters with independent VALU in their shadow ----
        f32x4 st0[4] = {}, st1[4] = {};
        s16x4 pp0[4], pp1[4];
        __builtin_amdgcn_s_setprio(1);
        // S^T(qi=0) = K * Q0^T
#pragma unroll
        for (int ks = 0; ks < 2; ++ks)
#pragma unroll
            for (int nt = 0; nt < 4; ++nt)
                st0[nt] = __builtin_amdgcn_mfma_f32_16x16x32_bf16(kf[nt][ks], aq[0][ks], st0[nt], 0, 0, 0);
        // S^T(qi=1) MFMAs interleaved with exp(qi=0) quads
#pragma unroll
        for (int nt = 0; nt < 4; ++nt) {
            st1[nt] = __builtin_amdgcn_mfma_f32_16x16x32_bf16(kf[nt][0], aq[1][0], st1[nt], 0, 0, 0);
            st1[nt] = __builtin_amdgcn_mfma_f32_16x16x32_bf16(kf[nt][1], aq[1][1], st1[nt], 0, 0, 0);
            pp0[nt] = exp_quad(st0[nt], mv[nt], C1);
        }
        // PV(qi=0) MFMAs interleaved with exp(qi=1) quads
#pragma unroll
        for (int nt = 0; nt < 4; ++nt) {
#pragma unroll
            for (int dt = 0; dt < 4; ++dt)
                acc_o[0][dt] = __builtin_amdgcn_mfma_f32_16x16x16bf16_1k(pp0[nt], vtf[nt][dt], acc_o[0][dt], 0, 0, 0);
            acc_l[0] = __builtin_amdgcn_mfma_f32_16x16x16bf16_1k(pp0[nt], ones, acc_l[0], 0, 0, 0);
            pp1[nt] = exp_quad(st1[nt], mv[nt], C1);
        }
        // PV(qi=1)
#pragma unroll
        for (int nt = 0; nt < 4; ++nt) {
#pragma unroll
            for (int dt = 0; dt < 4; ++dt)
                acc_o[1][dt] = __builtin_amdgcn_mfma_f32_16x16x16bf16_1k(pp1[nt], vtf[nt][dt], acc_o[1][dt], 0, 0, 0);
            acc_l[1] = __builtin_amdgcn_mfma_f32_16x16x16bf16_1k(pp1[nt], ones, acc_l[1], 0, 0, 0);
        }
        __builtin_amdgcn_s_setprio(0);
    }

    // epilogue: acc_l rows are already aligned with acc_o rows — no shuffles.
#pragma unroll
    for (int qi = 0; qi < 2; ++qi)
#pragma unroll
        for (int reg = 0; reg < 4; ++reg) {
            const float inv = 1.f / acc_l[qi][reg];
            const long row = rowbase + q0 + qi * 64 + quad * 4 + reg;
#pragma unroll
            for (int dt = 0; dt < 4; ++dt)
                Ctx[row * D_MODEL + h * DH + dt * 16 + l15] = (__bf16)(acc_o[qi][dt][reg] * inv);
        }
}

// ---------------------------------------------------------------------------
// Residual add + LayerNorm: one block per row of 1024. Y bf16, rest fp32.
// ---------------------------------------------------------------------------
__global__ __launch_bounds__(256) void ln_kernel(
    const __bf16* __restrict__ Y, const float* __restrict__ R,
    const float* __restrict__ gamma, const float* __restrict__ beta,
    float* __restrict__ Out)
{
    __shared__ float red[8];
    const long row = blockIdx.x;
    const int t = threadIdx.x;
    const int wave = t >> 6, lane = t & 63;
    float x[4];
    float s = 0.f, s2 = 0.f;
#pragma unroll
    for (int i = 0; i < 4; ++i) {
        const int idx = i * 256 + t;
        const float v = (float)Y[row * D_MODEL + idx] + R[row * D_MODEL + idx];
        x[i] = v; s += v; s2 += v * v;
    }
#pragma unroll
    for (int off = 32; off >= 1; off >>= 1) {
        s  += __shfl_xor(s, off, 64);
        s2 += __shfl_xor(s2, off, 64);
    }
    if (lane == 0) { red[wave] = s; red[4 + wave] = s2; }
    __syncthreads();
    s  = red[0] + red[1] + red[2] + red[3];
    s2 = red[4] + red[5] + red[6] + red[7];
    const float mu   = s * (1.f / 1024.f);
    const float var  = s2 * (1.f / 1024.f) - mu * mu;
    const float rstd = rsqrtf(var + 1e-5f);
#pragma unroll
    for (int i = 0; i < 4; ++i) {
        const int idx = i * 256 + t;
        Out[row * D_MODEL + idx] = (x[i] - mu) * rstd * gamma[idx] + beta[idx];
    }
}

// ---------------------------------------------------------------------------
// Buffers: ws = Qp(16.8MB, becomes ctx in-place) + Kp(16.8MB, reused as Y).
// d_out (33.55MB fp32) = Vp bf16 (16.8MB) + W*b bf16 (8.4MB) — both dead
// before ln_kernel overwrites d_out with the final output.
// ---------------------------------------------------------------------------
extern "C" void kernel_launch(void* const* d_in, const int* in_sizes, int n_in,
                              void* d_out, int out_size, void* d_ws, size_t ws_size,
                              hipStream_t stream)
{
    const float* q     = (const float*)d_in[0];
    const float* k     = (const float*)d_in[1];
    const float* v     = (const float*)d_in[2];
    const float* mask  = (const float*)d_in[3];
    const float* Wq    = (const float*)d_in[4];
    const float* Wk    = (const float*)d_in[5];
    const float* Wv    = (const float*)d_in[6];
    const float* Wo    = (const float*)d_in[7];
    const float* gamma = (const float*)d_in[8];
    const float* beta  = (const float*)d_in[9];
    float* out = (float*)d_out;

    const long NACT = (long)MTOT * D_MODEL;
    const long NW   = (long)D_MODEL * D_MODEL;

    __bf16* Qp = (__bf16*)d_ws;
    __bf16* Kp = Qp + NACT;
    __bf16* Vp = (__bf16*)d_out;
    __bf16* Wb = Vp + NACT;
    __bf16 *Wqb = Wb, *Wkb = Wb + NW, *Wvb = Wb + 2 * NW, *Wob = Wb + 3 * NW;
    __bf16* Y = Kp;   // Kp dead after attn

    cvt4_kernel<<<dim3(NW / 2048, 4), 256, 0, stream>>>(Wq, Wk, Wv, Wo, Wqb, Wkb, Wvb, Wob);

    gemm_qkv<<<dim3(MTOT / 128, D_MODEL / 128, 3), 256, 0, stream>>>(q, k, v, Wqb, Qp, Kp, Vp);

    attn_kernel<<<dim3(BS * NH, SEQ / 128), 256, 0, stream>>>(Qp, Kp, Vp, mask, Qp);

    gemm_bb<<<dim3(MTOT / 128, D_MODEL / 128), 256, 0, stream>>>(Qp, Wob, Y, MTOT, D_MODEL, D_MODEL);

    ln_kernel<<<MTOT, 256, 0, stream>>>(Y, q, gamma, beta, out);
}

// Round 4
// 358.416 us; speedup vs baseline: 2.4056x; 2.4056x over previous
//
#include <hip/hip_runtime.h>
#include <hip/hip_bf16.h>

typedef __bf16 bf16x8 __attribute__((ext_vector_type(8)));
typedef float  f32x4  __attribute__((ext_vector_type(4)));
typedef short  s16x4  __attribute__((ext_vector_type(4)));

#define D_MODEL 1024
#define SEQ 2048
#define BS 4
#define NH 16
#define DH 64
#define MTOT (BS * SEQ) /* 8192 */

#define AS1 __attribute__((address_space(1)))
#define AS3 __attribute__((address_space(3)))

template <typename T>
__device__ inline bf16x8 ld8(const T* p);

template <>
__device__ inline bf16x8 ld8<float>(const float* p) {
    f32x4 a = *(const f32x4*)p;
    f32x4 b = *(const f32x4*)(p + 4);
    bf16x8 r;
    r[0] = (__bf16)a[0]; r[1] = (__bf16)a[1]; r[2] = (__bf16)a[2]; r[3] = (__bf16)a[3];
    r[4] = (__bf16)b[0]; r[5] = (__bf16)b[1]; r[6] = (__bf16)b[2]; r[7] = (__bf16)b[3];
    return r;
}

template <>
__device__ inline bf16x8 ld8<__bf16>(const __bf16* p) {
    return *(const bf16x8*)p;
}

// ---------------------------------------------------------------------------
// fp32 -> bf16 weight conversion (4 matrices of NW elems each).
// ---------------------------------------------------------------------------
__global__ __launch_bounds__(256) void cvt4_kernel(
    const float* __restrict__ a, const float* __restrict__ b,
    const float* __restrict__ c, const float* __restrict__ e,
    __bf16* __restrict__ x, __bf16* __restrict__ y,
    __bf16* __restrict__ z, __bf16* __restrict__ w)
{
    const float* s = (blockIdx.y == 0) ? a : (blockIdx.y == 1) ? b : (blockIdx.y == 2) ? c : e;
    __bf16*      d = (blockIdx.y == 0) ? x : (blockIdx.y == 1) ? y : (blockIdx.y == 2) ? z : w;
    const long i = ((long)blockIdx.x * 256 + threadIdx.x) * 8;
    *(bf16x8*)(d + i) = ld8<float>(s + i);
}

// ---------------------------------------------------------------------------
// QKV projections, one dispatch (z selects A,B,C). BK=64 as two BK=32 panels.
// A fp32 -> bf16 through VGPRs; B bf16 via global_load_lds width=16.
// ---------------------------------------------------------------------------
__global__ __launch_bounds__(256) void gemm_qkv(
    const float* __restrict__ q, const float* __restrict__ k, const float* __restrict__ v,
    const __bf16* __restrict__ Wb,
    __bf16* __restrict__ Qp, __bf16* __restrict__ Kp, __bf16* __restrict__ Vp)
{
    __shared__ __align__(16) __bf16 As[2 * 4096];
    __shared__ __align__(16) __bf16 Bs[2 * 4096];
    const int K = D_MODEL, N = D_MODEL;
    const int z = blockIdx.z;
    const float* A = (z == 0) ? q : (z == 1) ? k : v;
    const __bf16* B = Wb + (long)z * D_MODEL * D_MODEL;
    __bf16* C = (z == 0) ? Qp : (z == 1) ? Kp : Vp;

    const int t = threadIdx.x;
    const int wave = t >> 6, lane = t & 63;
    const int quad = lane >> 4, l15 = lane & 15;
    const int wm = (wave >> 1) * 64, wn = (wave & 1) * 64;
    const long m0 = (long)blockIdx.x * 128;
    const long n0 = (long)blockIdx.y * 128;
    const int sr = t >> 2, sc = (t & 3) * 8;

    const __bf16* gB = B + (n0 + sr) * (long)K + sc;
    __bf16* lB0 = Bs + wave * 512;
    __bf16* lB1 = Bs + 2048 + wave * 512;
    __bf16* lB2 = Bs + 4096 + wave * 512;
    __bf16* lB3 = Bs + 6144 + wave * 512;

    f32x4 acc[4][4] = {};

    for (int k0 = 0; k0 < K; k0 += 64) {
        __builtin_amdgcn_global_load_lds((const AS1 void*)(gB + k0),               (AS3 void*)lB0, 16, 0, 0);
        __builtin_amdgcn_global_load_lds((const AS1 void*)(gB + 64 * K + k0),      (AS3 void*)lB1, 16, 0, 0);
        __builtin_amdgcn_global_load_lds((const AS1 void*)(gB + k0 + 32),          (AS3 void*)lB2, 16, 0, 0);
        __builtin_amdgcn_global_load_lds((const AS1 void*)(gB + 64 * K + k0 + 32), (AS3 void*)lB3, 16, 0, 0);
        *(bf16x8*)&As[sr * 32 + sc]               = ld8<float>(&A[(m0 + sr) * K + k0 + sc]);
        *(bf16x8*)&As[(sr + 64) * 32 + sc]        = ld8<float>(&A[(m0 + sr + 64) * K + k0 + sc]);
        *(bf16x8*)&As[4096 + sr * 32 + sc]        = ld8<float>(&A[(m0 + sr) * K + k0 + 32 + sc]);
        *(bf16x8*)&As[4096 + (sr + 64) * 32 + sc] = ld8<float>(&A[(m0 + sr + 64) * K + k0 + 32 + sc]);
        __syncthreads();
#pragma unroll
        for (int p = 0; p < 2; ++p) {
            bf16x8 af[4], bfr[4];
#pragma unroll
            for (int i = 0; i < 4; ++i) af[i]  = *(const bf16x8*)&As[p * 4096 + (wm + i * 16 + l15) * 32 + quad * 8];
#pragma unroll
            for (int i = 0; i < 4; ++i) bfr[i] = *(const bf16x8*)&Bs[p * 4096 + (wn + i * 16 + l15) * 32 + quad * 8];
#pragma unroll
            for (int i = 0; i < 4; ++i)
#pragma unroll
                for (int j = 0; j < 4; ++j)
                    acc[i][j] = __builtin_amdgcn_mfma_f32_16x16x32_bf16(af[i], bfr[j], acc[i][j], 0, 0, 0);
        }
        __syncthreads();
    }

#pragma unroll
    for (int i = 0; i < 4; ++i)
#pragma unroll
        for (int j = 0; j < 4; ++j) {
            const long r = m0 + wm + i * 16 + quad * 4;
            const long c = n0 + wn + j * 16 + l15;
#pragma unroll
            for (int reg = 0; reg < 4; ++reg)
                C[(r + reg) * N + c] = (__bf16)acc[i][j][reg];
        }
}

// ---------------------------------------------------------------------------
// bf16 GEMM for ctx @ Wo^T: two-panel BK=64, both operands via global_load_lds.
// ---------------------------------------------------------------------------
__global__ __launch_bounds__(256) void gemm_bb(
    const __bf16* __restrict__ A, const __bf16* __restrict__ B,
    __bf16* __restrict__ C, int M, int N, int K)
{
    __shared__ __align__(16) __bf16 As[2 * 4096];
    __shared__ __align__(16) __bf16 Bs[2 * 4096];
    const int t = threadIdx.x;
    const int wave = t >> 6, lane = t & 63;
    const int quad = lane >> 4, l15 = lane & 15;
    const int wm = (wave >> 1) * 64, wn = (wave & 1) * 64;
    const long m0 = (long)blockIdx.x * 128;
    const long n0 = (long)blockIdx.y * 128;
    const int sr = t >> 2, sc = (t & 3) * 8;

    const __bf16* gA = A + (m0 + sr) * (long)K + sc;
    const __bf16* gB = B + (n0 + sr) * (long)K + sc;
    __bf16* lA0 = As + wave * 512;
    __bf16* lA1 = As + 2048 + wave * 512;
    __bf16* lA2 = As + 4096 + wave * 512;
    __bf16* lA3 = As + 6144 + wave * 512;
    __bf16* lB0 = Bs + wave * 512;
    __bf16* lB1 = Bs + 2048 + wave * 512;
    __bf16* lB2 = Bs + 4096 + wave * 512;
    __bf16* lB3 = Bs + 6144 + wave * 512;

    f32x4 acc[4][4] = {};

    for (int k0 = 0; k0 < K; k0 += 64) {
        __builtin_amdgcn_global_load_lds((const AS1 void*)(gA + k0),               (AS3 void*)lA0, 16, 0, 0);
        __builtin_amdgcn_global_load_lds((const AS1 void*)(gA + 64 * K + k0),      (AS3 void*)lA1, 16, 0, 0);
        __builtin_amdgcn_global_load_lds((const AS1 void*)(gA + k0 + 32),          (AS3 void*)lA2, 16, 0, 0);
        __builtin_amdgcn_global_load_lds((const AS1 void*)(gA + 64 * K + k0 + 32), (AS3 void*)lA3, 16, 0, 0);
        __builtin_amdgcn_global_load_lds((const AS1 void*)(gB + k0),               (AS3 void*)lB0, 16, 0, 0);
        __builtin_amdgcn_global_load_lds((const AS1 void*)(gB + 64 * K + k0),      (AS3 void*)lB1, 16, 0, 0);
        __builtin_amdgcn_global_load_lds((const AS1 void*)(gB + k0 + 32),          (AS3 void*)lB2, 16, 0, 0);
        __builtin_amdgcn_global_load_lds((const AS1 void*)(gB + 64 * K + k0 + 32), (AS3 void*)lB3, 16, 0, 0);
        __syncthreads();
#pragma unroll
        for (int p = 0; p < 2; ++p) {
            bf16x8 af[4], bfr[4];
#pragma unroll
            for (int i = 0; i < 4; ++i) af[i]  = *(const bf16x8*)&As[p * 4096 + (wm + i * 16 + l15) * 32 + quad * 8];
#pragma unroll
            for (int i = 0; i < 4; ++i) bfr[i] = *(const bf16x8*)&Bs[p * 4096 + (wn + i * 16 + l15) * 32 + quad * 8];
#pragma unroll
            for (int i = 0; i < 4; ++i)
#pragma unroll
                for (int j = 0; j < 4; ++j)
                    acc[i][j] = __builtin_amdgcn_mfma_f32_16x16x32_bf16(af[i], bfr[j], acc[i][j], 0, 0, 0);
        }
        __syncthreads();
    }

#pragma unroll
    for (int i = 0; i < 4; ++i)
#pragma unroll
        for (int j = 0; j < 4; ++j) {
            const long r = m0 + wm + i * 16 + quad * 4;
            const long c = n0 + wn + j * 16 + l15;
#pragma unroll
            for (int reg = 0; reg < 4; ++reg)
                C[(r + reg) * N + c] = (__bf16)acc[i][j][reg];
        }
}

// ---------------------------------------------------------------------------
// Flash attention v9 = v7 compute body (VGPR 104, no spill) + two cheap
// levers from the failed v8 (whose dual-state interleave spilled to scratch
// under launch_bounds(256,4): WRITE_SIZE 16MB -> 1.6GB. Reverted.):
//  - grid (bh, qt): the 16 qt-blocks sharing one (b,h)'s K/V are 64-apart
//    in dispatch order -> same XCD L2 (64 % 8 == 0) -> K/V refetch collapses.
//  - s_setprio(1) across compute (T5): blocks on a CU run phase-independent.
// ---------------------------------------------------------------------------
__global__ __launch_bounds__(256) void attn_kernel(
    const __bf16* Qp, const __bf16* __restrict__ Kp, const __bf16* __restrict__ Vp,
    const float* __restrict__ mask, __bf16* Ctx)
{
    __shared__ __align__(16) __bf16 Ks[2][64][72];   // [buf][key][d]
    __shared__ __align__(16) __bf16 Vt[2][64][76];   // [buf][d][key], rows 152B
    __shared__ __align__(16) float  Ms[2][64];       // mask * -1e9 * log2e

    const int t = threadIdx.x;
    const int wave = t >> 6, lane = t & 63;
    const int quad = lane >> 4, l15 = lane & 15;
    const int bh = blockIdx.x;            // 0..63  (fast dim -> XCD affinity)
    const int qt = blockIdx.y;            // 0..15
    const int b = bh >> 4, h = bh & 15;
    const long rowbase = (long)b * SEQ;
    const int q0 = qt * 128 + wave * 16;

    // Q fragments, B-operand layout (q=l15, d=quad*8+j), 2 q-tiles.
    bf16x8 aq[2][2];
#pragma unroll
    for (int qi = 0; qi < 2; ++qi) {
        const long qrow = rowbase + q0 + qi * 64 + l15;
        const __bf16* qptr = Qp + qrow * D_MODEL + h * DH + quad * 8;
        aq[qi][0] = *(const bf16x8*)(qptr);
        aq[qi][1] = *(const bf16x8*)(qptr + 32);
    }

    // ones B-fragment for the l-MFMA (bf16 1.0 = 0x3F80)
    const s16x4 ones = {(short)0x3F80, (short)0x3F80, (short)0x3F80, (short)0x3F80};

    f32x4 acc_l[2] = {};      // [qi]; C-layout rows q=quad*4+reg (cols identical)
    f32x4 acc_o[2][4] = {};   // [qi][d-tile]; C-layout: d=dt*16+l15, q=quad*4+reg

    const int sr = t >> 2, sc = (t & 3) * 16;        // K staging
    const int kp2 = (t >> 3) * 2, dc = (t & 7) * 8;  // V staging (key pairs)
    const float C1 = 0.125f * 1.44269504f;
    const float C2 = -1e9f * 1.44269504f;

    // register staging bases
    const __bf16* kbase = Kp + (rowbase + sr) * D_MODEL + h * DH + sc;
    const __bf16* vbase = Vp + (rowbase + kp2) * D_MODEL + h * DH + dc;

    // prologue: stage tile 0 into registers
    bf16x8 kr0 = *(const bf16x8*)(kbase);
    bf16x8 kr1 = *(const bf16x8*)(kbase + 8);
    bf16x8 vr0 = *(const bf16x8*)(vbase);
    bf16x8 vr1 = *(const bf16x8*)(vbase + D_MODEL);
    float  mreg = (t < 64) ? mask[rowbase + t] * C2 : 0.f;

    for (int kt = 0; kt < SEQ / 64; ++kt) {
        const int buf = kt & 1;
        // ---- write staged registers -> LDS[buf] ----
        *(bf16x8*)&Ks[buf][sr][sc]     = kr0;
        *(bf16x8*)&Ks[buf][sr][sc + 8] = kr1;
#pragma unroll
        for (int e = 0; e < 8; ++e) {
            union { __bf16 h2[2]; unsigned u; } pk;
            pk.h2[0] = vr0[e]; pk.h2[1] = vr1[e];
            *(unsigned*)&Vt[buf][dc + e][kp2] = pk.u;
        }
        if (t < 64) Ms[buf][t] = mreg;
        __syncthreads();

        // ---- issue tile kt+1 global loads; consumed before the next barrier ----
        {
            const int ktn = (kt + 1 < SEQ / 64) ? kt + 1 : kt;
            const long off = (long)ktn * 64 * D_MODEL;
            kr0 = *(const bf16x8*)(kbase + off);
            kr1 = *(const bf16x8*)(kbase + off + 8);
            vr0 = *(const bf16x8*)(vbase + off);
            vr1 = *(const bf16x8*)(vbase + off + D_MODEL);
            mreg = (t < 64) ? mask[rowbase + ktn * 64 + t] * C2 : 0.f;
        }

        // ---- hoisted fragments (shared by both q-tiles) ----
        bf16x8 kf[4][2];     // A-op: K[key=nt*16+l15][d=ks*32+quad*8+j]
#pragma unroll
        for (int nt = 0; nt < 4; ++nt)
#pragma unroll
            for (int ks = 0; ks < 2; ++ks)
                kf[nt][ks] = *(const bf16x8*)&Ks[buf][nt * 16 + l15][ks * 32 + quad * 8];
        s16x4 vtf[4][4];     // B-op (16x16x16): V[key=nt*16+quad*4+e][d=dt*16+l15]
#pragma unroll
        for (int nt = 0; nt < 4; ++nt)
#pragma unroll
            for (int dt = 0; dt < 4; ++dt)
                vtf[nt][dt] = *(const s16x4*)&Vt[buf][dt * 16 + l15][nt * 16 + quad * 4];
        f32x4 mv[4];         // mask bias, elem reg -> key nt*16+quad*4+reg
#pragma unroll
        for (int nt = 0; nt < 4; ++nt)
            mv[nt] = *(const f32x4*)&Ms[buf][nt * 16 + quad * 4];

        __builtin_amdgcn_s_setprio(1);
#pragma unroll
        for (int qi = 0; qi < 2; ++qi) {
            // S^T = K * Q^T
            f32x4 st[4] = {};
#pragma unroll
            for (int ks = 0; ks < 2; ++ks)
#pragma unroll
                for (int nt = 0; nt < 4; ++nt)
                    st[nt] = __builtin_amdgcn_mfma_f32_16x16x32_bf16(kf[nt][ks], aq[qi][ks], st[nt], 0, 0, 0);
            // p = exp2(s*C1 + m'), packed pairwise -> 16x16x16 A-fragments
            s16x4 pp[4];
#pragma unroll
            for (int nt = 0; nt < 4; ++nt) {
                float pv0 = __builtin_amdgcn_exp2f(fmaf(st[nt][0], C1, mv[nt][0]));
                float pv1 = __builtin_amdgcn_exp2f(fmaf(st[nt][1], C1, mv[nt][1]));
                float pv2 = __builtin_amdgcn_exp2f(fmaf(st[nt][2], C1, mv[nt][2]));
                float pv3 = __builtin_amdgcn_exp2f(fmaf(st[nt][3], C1, mv[nt][3]));
                union { __hip_bfloat162 h2[2]; s16x4 s; } u;
                u.h2[0] = __float22bfloat162_rn(float2{pv0, pv1});
                u.h2[1] = __float22bfloat162_rn(float2{pv2, pv3});
                pp[nt] = u.s;
            }
            // O += P * V ; l += P * 1 (on the MFMA pipe)
#pragma unroll
            for (int nt = 0; nt < 4; ++nt) {
#pragma unroll
                for (int dt = 0; dt < 4; ++dt)
                    acc_o[qi][dt] = __builtin_amdgcn_mfma_f32_16x16x16bf16_1k(pp[nt], vtf[nt][dt], acc_o[qi][dt], 0, 0, 0);
                acc_l[qi] = __builtin_amdgcn_mfma_f32_16x16x16bf16_1k(pp[nt], ones, acc_l[qi], 0, 0, 0);
            }
        }
        __builtin_amdgcn_s_setprio(0);
    }

    // epilogue: acc_l rows are already aligned with acc_o rows — no shuffles.
#pragma unroll
    for (int qi = 0; qi < 2; ++qi)
#pragma unroll
        for (int reg = 0; reg < 4; ++reg) {
            const float inv = 1.f / acc_l[qi][reg];
            const long row = rowbase + q0 + qi * 64 + quad * 4 + reg;
#pragma unroll
            for (int dt = 0; dt < 4; ++dt)
                Ctx[row * D_MODEL + h * DH + dt * 16 + l15] = (__bf16)(acc_o[qi][dt][reg] * inv);
        }
}

// ---------------------------------------------------------------------------
// Residual add + LayerNorm: one block per row of 1024. Y bf16, rest fp32.
// ---------------------------------------------------------------------------
__global__ __launch_bounds__(256) void ln_kernel(
    const __bf16* __restrict__ Y, const float* __restrict__ R,
    const float* __restrict__ gamma, const float* __restrict__ beta,
    float* __restrict__ Out)
{
    __shared__ float red[8];
    const long row = blockIdx.x;
    const int t = threadIdx.x;
    const int wave = t >> 6, lane = t & 63;
    float x[4];
    float s = 0.f, s2 = 0.f;
#pragma unroll
    for (int i = 0; i < 4; ++i) {
        const int idx = i * 256 + t;
        const float v = (float)Y[row * D_MODEL + idx] + R[row * D_MODEL + idx];
        x[i] = v; s += v; s2 += v * v;
    }
#pragma unroll
    for (int off = 32; off >= 1; off >>= 1) {
        s  += __shfl_xor(s, off, 64);
        s2 += __shfl_xor(s2, off, 64);
    }
    if (lane == 0) { red[wave] = s; red[4 + wave] = s2; }
    __syncthreads();
    s  = red[0] + red[1] + red[2] + red[3];
    s2 = red[4] + red[5] + red[6] + red[7];
    const float mu   = s * (1.f / 1024.f);
    const float var  = s2 * (1.f / 1024.f) - mu * mu;
    const float rstd = rsqrtf(var + 1e-5f);
#pragma unroll
    for (int i = 0; i < 4; ++i) {
        const int idx = i * 256 + t;
        Out[row * D_MODEL + idx] = (x[i] - mu) * rstd * gamma[idx] + beta[idx];
    }
}

// ---------------------------------------------------------------------------
// Buffers: ws = Qp(16.8MB, becomes ctx in-place) + Kp(16.8MB, reused as Y).
// d_out (33.55MB fp32) = Vp bf16 (16.8MB) + W*b bf16 (8.4MB) — both dead
// before ln_kernel overwrites d_out with the final output.
// ---------------------------------------------------------------------------
extern "C" void kernel_launch(void* const* d_in, const int* in_sizes, int n_in,
                              void* d_out, int out_size, void* d_ws, size_t ws_size,
                              hipStream_t stream)
{
    const float* q     = (const float*)d_in[0];
    const float* k     = (const float*)d_in[1];
    const float* v     = (const float*)d_in[2];
    const float* mask  = (const float*)d_in[3];
    const float* Wq    = (const float*)d_in[4];
    const float* Wk    = (const float*)d_in[5];
    const float* Wv    = (const float*)d_in[6];
    const float* Wo    = (const float*)d_in[7];
    const float* gamma = (const float*)d_in[8];
    const float* beta  = (const float*)d_in[9];
    float* out = (float*)d_out;

    const long NACT = (long)MTOT * D_MODEL;
    const long NW   = (long)D_MODEL * D_MODEL;

    __bf16* Qp = (__bf16*)d_ws;
    __bf16* Kp = Qp + NACT;
    __bf16* Vp = (__bf16*)d_out;
    __bf16* Wb = Vp + NACT;
    __bf16 *Wqb = Wb, *Wkb = Wb + NW, *Wvb = Wb + 2 * NW, *Wob = Wb + 3 * NW;
    __bf16* Y = Kp;   // Kp dead after attn

    cvt4_kernel<<<dim3(NW / 2048, 4), 256, 0, stream>>>(Wq, Wk, Wv, Wo, Wqb, Wkb, Wvb, Wob);

    gemm_qkv<<<dim3(MTOT / 128, D_MODEL / 128, 3), 256, 0, stream>>>(q, k, v, Wqb, Qp, Kp, Vp);

    attn_kernel<<<dim3(BS * NH, SEQ / 128), 256, 0, stream>>>(Qp, Kp, Vp, mask, Qp);

    gemm_bb<<<dim3(MTOT / 128, D_MODEL / 128), 256, 0, stream>>>(Qp, Wob, Y, MTOT, D_MODEL, D_MODEL);

    ln_kernel<<<MTOT, 256, 0, stream>>>(Y, q, gamma, beta, out);
}